// Round 12
// baseline (692.957 us; speedup 1.0000x reference)
//
#include <hip/hip_runtime.h>

#define TT 2000
#define BB 64
#define HH 256
#define BH (BB*HH)
#define CH 8            // chunk = 8 time steps
#define NCH (TT/CH)     // 250 chunks
#define CROWS 128       // w_recP rows cached in LDS (s in [0,128))

__device__ __forceinline__ float clip01(float x) { return fminf(fmaxf(x, 0.0f), 1.0f); }

// ---------------- weight prep ----------------
// w_inT[k][h]     = w_in[h][k]       (GEMM)
// w_recP[s][4l+j] = w_rec[l+64j][s]  (packed gather rows; R10/R11-verified)
__global__ void transpose2(const float* __restrict__ w_in, const float* __restrict__ w_rec,
                           float* __restrict__ w_inT, float* __restrict__ w_recP) {
    int idx = blockIdx.x * 256 + threadIdx.x;   // 65536 per matrix
    int h = idx >> 8, s = idx & 255;            // coalesced read over s
    w_inT[s * HH + h] = w_in[idx];
    int l = h & 63, j = h >> 6;
    w_recP[s * HH + 4 * l + j] = w_rec[idx];
}

// ---------------- f32 GEMM: xw[n,h] = sum_k X[n,k] * w_inT[k,h] ----------------
// (R9-exact, BK=32 — measured ~204us; BK=64 was slower)
#define BM 128
#define BN 128
#define BK 32
__global__ __launch_bounds__(256) void gemm_xw(const float* __restrict__ X,
                                               const float* __restrict__ WT,
                                               float* __restrict__ OutXW) {
    __shared__ __align__(16) float XsT[BK][BM + 4];   // transposed: [k][row]
    __shared__ __align__(16) float Ws[BK][BN + 4];    // [k][col]
    int tid = threadIdx.x;
    int n0 = blockIdx.x * BM;
    int h0 = blockIdx.y * BN;
    int ty = tid >> 4, tx = tid & 15;
    float acc[8][8] = {};

    for (int kc = 0; kc < HH; kc += BK) {
        {
            int r = tid & 127, kseg = (tid >> 7) * 16;
            const float* src = X + (size_t)(n0 + r) * HH + kc + kseg;
#pragma unroll
            for (int q = 0; q < 4; q++) {
                float4 xv = *(const float4*)(src + q * 4);
                XsT[kseg + q * 4 + 0][r] = xv.x;
                XsT[kseg + q * 4 + 1][r] = xv.y;
                XsT[kseg + q * 4 + 2][r] = xv.z;
                XsT[kseg + q * 4 + 3][r] = xv.w;
            }
        }
        {
            int krow = tid >> 3, cs = (tid & 7) * 16;
            const float* src = WT + (size_t)(kc + krow) * HH + h0 + cs;
#pragma unroll
            for (int q = 0; q < 4; q++) {
                float4 wv = *(const float4*)(src + q * 4);
                *(float4*)&Ws[krow][cs + q * 4] = wv;
            }
        }
        __syncthreads();
#pragma unroll 4
        for (int kk = 0; kk < BK; kk++) {
            float4 a0 = *(const float4*)&XsT[kk][ty * 8];
            float4 a1 = *(const float4*)&XsT[kk][ty * 8 + 4];
            float4 b0 = *(const float4*)&Ws[kk][tx * 8];
            float4 b1 = *(const float4*)&Ws[kk][tx * 8 + 4];
            float a[8] = {a0.x, a0.y, a0.z, a0.w, a1.x, a1.y, a1.z, a1.w};
            float bb[8] = {b0.x, b0.y, b0.z, b0.w, b1.x, b1.y, b1.z, b1.w};
#pragma unroll
            for (int r = 0; r < 8; r++)
#pragma unroll
                for (int c = 0; c < 8; c++)
                    acc[r][c] += a[r] * bb[c];
        }
        __syncthreads();
    }
#pragma unroll
    for (int r = 0; r < 8; r++) {
        int n = n0 + ty * 8 + r;
        int b = n / TT;
        int t = n - b * TT;
        float* dst = OutXW + ((size_t)t * BB + b) * HH + h0 + tx * 8;
        float4 s0 = {acc[r][0], acc[r][1], acc[r][2], acc[r][3]};
        float4 s1 = {acc[r][4], acc[r][5], acc[r][6], acc[r][7]};
        *(float4*)dst = s0;
        *(float4*)(dst + 4) = s1;
    }
}

// ---------------- sequential LIF scan ----------------
// R9 skeleton. Gather changes only:
//  - high half (m2,m3; global/L2): extract 2 smallest (EX1), ISSUE loads FIRST,
//    accumulate LAST (after low half) -> L2 latency hides under LDS gathers.
//  - low half (m0,m1; LDS wc): 2-slot batched prefix + serial remainder.
// Accumulate order m0,m1,m2,m3 ascending == R9 (bitwise). Dummy slots use
// weight 0.0 (fma(0,x,r)=r exact; R11-verified).

// extract next index (ascending) from mask pair A(bits 0..63) B(64..127)
#define EX1(A, B, SOUT) do {                                                        \
    bool _ua = ((A) != 0ull);                                                       \
    unsigned long long _pk = _ua ? (A) : (B);                                       \
    int _bit = (int)__builtin_ctzll(_pk | 0x8000000000000000ull);                   \
    SOUT = (_ua ? 0 : 64) + _bit;                                                   \
    unsigned long long _pc = _pk & (_pk - 1ull);                                    \
    A = _ua ? _pc : (A);                                                            \
    B = _ua ? (B) : _pc;                                                            \
} while (0)

#define STEP()                                                                      \
    do {                                                                            \
        bool z[4];                                                                  \
        _Pragma("unroll")                                                           \
        for (int j = 0; j < 4; j++) {                                               \
            float vd = vv[j] + am[j] * (ii[j] - vv[j]);     /* v + DT*tmi*(-v+i) */ \
            float id = ii[j] - bs[j] * ii[j];               /* i - DT*tsi*i    */   \
            z[j] = (vd - 1.0f) > 0.0f;                                              \
            float zf = z[j] ? 1.0f : 0.0f;                                          \
            vv[j] = z[j] ? 0.0f : vd;                                               \
            ii[j] = (id + cur[j]) + racc[j];                /* (i_dec+xw)+rec */    \
            __builtin_nontemporal_store(zf, &outp[stoff + j * 64]);                 \
            zl[j] = zf;                                                             \
        }                                                                           \
        stoff += BH;                                                                \
        unsigned long long m0 = __ballot(z[0]);                                     \
        unsigned long long m1 = __ballot(z[1]);                                     \
        unsigned long long m2 = __ballot(z[2]);                                     \
        unsigned long long m3 = __ballot(z[3]);                                     \
        racc[0] = 0.0f; racc[1] = 0.0f; racc[2] = 0.0f; racc[3] = 0.0f;             \
        unsigned long long a2 = m2, b3 = m3;                                        \
        float4 eh0 = {0.f, 0.f, 0.f, 0.f}, eh1 = {0.f, 0.f, 0.f, 0.f};              \
        float wh1 = 0.0f;                                                           \
        bool hasH = (m2 | m3) != 0ull;                                              \
        if (hasH) {   /* issue global loads EARLY */                                \
            int t0, t1;                                                             \
            EX1(a2, b3, t0);                                                        \
            wh1 = ((a2 | b3) != 0ull) ? 1.0f : 0.0f;                                \
            EX1(a2, b3, t1);                                                        \
            eh0 = *(const float4*)(w_recP + ((size_t)(128 + t0) << 8) + 4 * lane);  \
            eh1 = *(const float4*)(w_recP + ((size_t)(128 + t1) << 8) + 4 * lane);  \
        }                                                                           \
        if ((m0 | m1) != 0ull) {   /* low half: LDS, 2-slot prefix */               \
            unsigned long long a0 = m0, b1 = m1;                                    \
            int s0, s1;                                                             \
            EX1(a0, b1, s0);                                                        \
            float wl1 = ((a0 | b1) != 0ull) ? 1.0f : 0.0f;                          \
            EX1(a0, b1, s1);                                                        \
            float4 el0 = *(const float4*)(wc + (s0 << 8) + 4 * lane);               \
            float4 el1 = *(const float4*)(wc + (s1 << 8) + 4 * lane);               \
            racc[0] += el0.x; racc[1] += el0.y; racc[2] += el0.z; racc[3] += el0.w; \
            racc[0] += wl1 * el1.x; racc[1] += wl1 * el1.y;                         \
            racc[2] += wl1 * el1.z; racc[3] += wl1 * el1.w;                         \
            while (a0) { int bit = __builtin_ctzll(a0); a0 &= a0 - 1;               \
                float4 e = *(const float4*)(wc + (bit << 8) + 4 * lane);            \
                racc[0] += e.x; racc[1] += e.y; racc[2] += e.z; racc[3] += e.w; }   \
            while (b1) { int bit = __builtin_ctzll(b1); b1 &= b1 - 1;               \
                float4 e = *(const float4*)(wc + ((64 + bit) << 8) + 4 * lane);     \
                racc[0] += e.x; racc[1] += e.y; racc[2] += e.z; racc[3] += e.w; }   \
        }                                                                           \
        if (hasH) {   /* accumulate high LAST (order m2,m3 ascending) */            \
            racc[0] += eh0.x; racc[1] += eh0.y; racc[2] += eh0.z; racc[3] += eh0.w; \
            racc[0] += wh1 * eh1.x; racc[1] += wh1 * eh1.y;                         \
            racc[2] += wh1 * eh1.z; racc[3] += wh1 * eh1.w;                         \
            while (a2) { int bit = __builtin_ctzll(a2); a2 &= a2 - 1;               \
                float4 e = *(const float4*)(w_recP + ((size_t)(128 + bit) << 8) + 4 * lane); \
                racc[0] += e.x; racc[1] += e.y; racc[2] += e.z; racc[3] += e.w; }   \
            while (b3) { int bit = __builtin_ctzll(b3); b3 &= b3 - 1;               \
                float4 e = *(const float4*)(w_recP + ((size_t)(192 + bit) << 8) + 4 * lane); \
                racc[0] += e.x; racc[1] += e.y; racc[2] += e.z; racc[3] += e.w; }   \
        }                                                                           \
    } while (0)

__global__ __launch_bounds__(128) void scan_lif(const float* __restrict__ tau_syn,
                                                const float* __restrict__ tau_mem,
                                                const float* __restrict__ w_recP,
                                                float* __restrict__ outp) {
    const float DT = 0.001f;
    __shared__ __align__(16) float ring[2 * CH * HH];     // 16 KB
    __shared__ __align__(16) float wc[CROWS * HH];        // 128 KB: w_recP rows 0..127
    int b = blockIdx.x;
    int lane = threadIdx.x & 63;
    int wid = threadIdx.x >> 6;

    // ---- cooperative wcache fill ----
    {
        const float4* src = (const float4*)w_recP;
        float4* dst = (float4*)wc;
#pragma unroll
        for (int q = 0; q < (CROWS * HH / 4) / 128; ++q)   // 64 iters
            dst[q * 128 + threadIdx.x] = src[q * 128 + threadIdx.x];
    }

    if (wid == 1) {
        // ---- producer: stage xw chunks into LDS ring (R9-verbatim) ----
        float4 rb[CH];
#pragma unroll
        for (int r = 0; r < CH; ++r)
            rb[r] = *(const float4*)(outp + ((size_t)r * BB + b) * HH + 4 * lane);
#pragma unroll
        for (int r = 0; r < CH; ++r)
            *(float4*)&ring[r * HH + 4 * lane] = rb[r];
        __syncthreads();
        for (int c = 0; c < NCH; ++c) {
            if (c + 1 < NCH) {
                int t0 = (c + 1) * CH;
                int lb = ((c + 1) & 1) * (CH * HH);
                float4 sb[CH];
#pragma unroll
                for (int r = 0; r < CH; ++r)
                    sb[r] = *(const float4*)(outp + ((size_t)(t0 + r) * BB + b) * HH + 4 * lane);
#pragma unroll
                for (int r = 0; r < CH; ++r)
                    *(float4*)&ring[lb + r * HH + 4 * lane] = sb[r];
            }
            __syncthreads();
        }
        return;
    }

    // ---- consumer wave (R9-verbatim skeleton) ----
    int off = b * HH + lane;
    float am[4], bs[4];
#pragma unroll
    for (int j = 0; j < 4; j++) {
        am[j] = DT * clip01(tau_mem[lane + 64 * j]);
        bs[j] = DT * clip01(tau_syn[lane + 64 * j]);
    }

    float vv[4] = {0.f, 0.f, 0.f, 0.f};
    float ii[4] = {0.f, 0.f, 0.f, 0.f};
    float racc[4] = {0.f, 0.f, 0.f, 0.f};
    float zl[4] = {0.f, 0.f, 0.f, 0.f};
    float cur[4], nxt[4];
    unsigned stoff = (unsigned)off;

    __syncthreads();   // wcache + chunk 0 staged

    for (int c = 0; c < NCH; ++c) {
        int lb = (c & 1) * (CH * HH);
#pragma unroll
        for (int j = 0; j < 4; j++)
            cur[j] = ring[lb + lane + 64 * j];
        for (int u = 0; u < CH - 1; ++u) {
#pragma unroll
            for (int j = 0; j < 4; j++)
                nxt[j] = ring[lb + (u + 1) * HH + lane + 64 * j];
            STEP();
#pragma unroll
            for (int j = 0; j < 4; j++)
                cur[j] = nxt[j];
        }
        STEP();        // u = CH-1
        __syncthreads();
    }

    // final state: z_f, v_f, i_f (from registers)
#pragma unroll
    for (int j = 0; j < 4; j++) {
        outp[(size_t)TT * BH + b * HH + lane + 64 * j] = zl[j];
        outp[(size_t)TT * BH + BH + b * HH + lane + 64 * j] = vv[j];
        outp[(size_t)TT * BH + 2 * BH + b * HH + lane + 64 * j] = ii[j];
    }
}

extern "C" void kernel_launch(void* const* d_in, const int* in_sizes, int n_in,
                              void* d_out, int out_size, void* d_ws, size_t ws_size,
                              hipStream_t stream) {
    const float* x       = (const float*)d_in[0];
    const float* w_in    = (const float*)d_in[1];
    const float* w_rec   = (const float*)d_in[2];
    const float* tau_syn = (const float*)d_in[3];
    const float* tau_mem = (const float*)d_in[4];
    float* out = (float*)d_out;

    float* w_inT  = (float*)d_ws;           // 65536 floats
    float* w_recP = w_inT + HH * HH;        // 65536 floats

    transpose2<<<256, 256, 0, stream>>>(w_in, w_rec, w_inT, w_recP);

    dim3 ggrid((BB * TT) / BM, HH / BN);    // (1000, 2)
    gemm_xw<<<ggrid, 256, 0, stream>>>(x, w_inT, out);

    scan_lif<<<BB, 128, 0, stream>>>(tau_syn, tau_mem, w_recP, out);
}

// Round 13
// 475.769 us; speedup vs baseline: 1.4565x; 1.4565x over previous
//
#include <hip/hip_runtime.h>

#define TT 2000
#define BB 64
#define HH 256
#define BH (BB*HH)
#define CH 8            // scan chunk = 8 time steps
#define NCH (TT/CH)     // 250 chunks
#define CROWS 128       // w_recP rows cached in LDS (s in [0,128))
#define NXT 1000        // GEMM n'-tiles (each covers 2 t-values x all b)
#define SCANB 64        // scan blocks (one per batch)

#define BM 128
#define BN 128
#define BK 32

__device__ __forceinline__ float clip01(float x) { return fminf(fmaxf(x, 0.0f), 1.0f); }

// ---------------- weight prep ----------------
// w_inT[k][h]     = w_in[h][k]       (GEMM)
// w_recP[s][4l+j] = w_rec[l+64j][s]  (packed gather rows; value-verified R10/R11/R12)
__global__ void transpose2(const float* __restrict__ w_in, const float* __restrict__ w_rec,
                           float* __restrict__ w_inT, float* __restrict__ w_recP) {
    int idx = blockIdx.x * 256 + threadIdx.x;   // 65536 per matrix
    int h = idx >> 8, s = idx & 255;            // coalesced read over s
    w_inT[s * HH + h] = w_in[idx];
    int l = h & 63, j = h >> 6;
    w_recP[s * HH + 4 * l + j] = w_rec[idx];
}

// ---------------- fused kernel: GEMM blocks + scan blocks, flag-synced ----------------
// blocks [0,64): scan (R9-verbatim skeleton; producer waits on flags).
// blocks [64,2064): GEMM tile, t-major (tile x: rows n'=t*64+b in [128x,128x+128)),
//   releases flags[x] += 1 (ready when ==2, both h-halves done).
// One ACQUIRE load per scan chunk (not per poll) -> one L2 invalidate per chunk.

__global__ __launch_bounds__(256) void fused(const float* __restrict__ X,
                                             const float* __restrict__ tau_syn,
                                             const float* __restrict__ tau_mem,
                                             const float* __restrict__ w_inT,
                                             const float* __restrict__ w_recP,
                                             int* flags,
                                             float* outp) {
    __shared__ __align__(16) char ldsraw[147456];   // union: scan{ring16K+wc128K} / gemm{XsT+Ws 33K}
    int gx = blockIdx.x;

    if (gx >= SCANB) {
        // ================= GEMM block (R9 math, t-major tiles) =================
        float* XsT = (float*)ldsraw;                 // [BK][BM+4]
        float* Ws  = XsT + BK * (BM + 4);            // [BK][BN+4]
        int gg = gx - SCANB;
        int xt = gg >> 1, yy = gg & 1;
        int n0 = xt * BM, h0 = yy * BN;
        int tid = threadIdx.x;
        int ty = tid >> 4, tx = tid & 15;
        float acc[8][8] = {};

        for (int kc = 0; kc < HH; kc += BK) {
            {   // X tile: row n' = t*64+b  ->  X[(b*TT + t)*HH + k]
                int r = tid & 127, kseg = (tid >> 7) * 16;
                int np = n0 + r;
                const float* src = X + ((size_t)(np & 63) * TT + (np >> 6)) * HH + kc + kseg;
#pragma unroll
                for (int q = 0; q < 4; q++) {
                    float4 xv = *(const float4*)(src + q * 4);
                    XsT[(kseg + q * 4 + 0) * (BM + 4) + r] = xv.x;
                    XsT[(kseg + q * 4 + 1) * (BM + 4) + r] = xv.y;
                    XsT[(kseg + q * 4 + 2) * (BM + 4) + r] = xv.z;
                    XsT[(kseg + q * 4 + 3) * (BM + 4) + r] = xv.w;
                }
            }
            {
                int krow = tid >> 3, cs = (tid & 7) * 16;
                const float* src = w_inT + (size_t)(kc + krow) * HH + h0 + cs;
#pragma unroll
                for (int q = 0; q < 4; q++) {
                    float4 wv = *(const float4*)(src + q * 4);
                    *(float4*)&Ws[krow * (BN + 4) + cs + q * 4] = wv;
                }
            }
            __syncthreads();
#pragma unroll 4
            for (int kk = 0; kk < BK; kk++) {
                float4 a0 = *(const float4*)&XsT[kk * (BM + 4) + ty * 8];
                float4 a1 = *(const float4*)&XsT[kk * (BM + 4) + ty * 8 + 4];
                float4 b0 = *(const float4*)&Ws[kk * (BN + 4) + tx * 8];
                float4 b1 = *(const float4*)&Ws[kk * (BN + 4) + tx * 8 + 4];
                float a[8] = {a0.x, a0.y, a0.z, a0.w, a1.x, a1.y, a1.z, a1.w};
                float bb[8] = {b0.x, b0.y, b0.z, b0.w, b1.x, b1.y, b1.z, b1.w};
#pragma unroll
                for (int r = 0; r < 8; r++)
#pragma unroll
                    for (int c = 0; c < 8; c++)
                        acc[r][c] += a[r] * bb[c];
            }
            __syncthreads();
        }
#pragma unroll
        for (int r = 0; r < 8; r++) {
            int np = n0 + ty * 8 + r;                 // n' IS the out row (t*BB+b)
            float* dst = outp + (size_t)np * HH + h0 + tx * 8;
            float4 s0 = {acc[r][0], acc[r][1], acc[r][2], acc[r][3]};
            float4 s1 = {acc[r][4], acc[r][5], acc[r][6], acc[r][7]};
            *(float4*)dst = s0;
            *(float4*)(dst + 4) = s1;
        }
        __syncthreads();   // all waves' stores complete (vmcnt(0) before barrier)
        if (tid == 0)
            __hip_atomic_fetch_add(&flags[xt], 1, __ATOMIC_RELEASE, __HIP_MEMORY_SCOPE_AGENT);
        return;
    }

    // ================= scan block (R9-verbatim skeleton) =================
    if (threadIdx.x >= 128) return;   // waves 2,3 unused (exit before any barrier)
    const float DT = 0.001f;
    float* ring = (float*)ldsraw;                  // 2*CH*HH floats = 16 KB
    float* wc   = ring + 2 * CH * HH;              // CROWS*HH floats = 128 KB
    int b = gx;
    int lane = threadIdx.x & 63;
    int wid = threadIdx.x >> 6;

    // cooperative wcache fill: w_recP rows 0..127 (128 threads, 64 iters)
    {
        const float4* src = (const float4*)w_recP;
        float4* dst = (float4*)wc;
#pragma unroll
        for (int q = 0; q < (CROWS * HH / 4) / 128; ++q)
            dst[q * 128 + threadIdx.x] = src[q * 128 + threadIdx.x];
    }

    if (wid == 1) {
        // ---- producer: flag-wait then stage xw chunks into LDS ring ----
        // relaxed spins + single acquire per chunk (one L2 invalidate each)
#define WAITC(CC) do { int x0 = 4 * (CC);                                            \
            _Pragma("unroll")                                                        \
            for (int k = 0; k < 4; ++k)                                              \
                while (__hip_atomic_load(&flags[x0 + k], __ATOMIC_RELAXED,           \
                                         __HIP_MEMORY_SCOPE_AGENT) != 2)             \
                    __builtin_amdgcn_s_sleep(8);                                     \
            (void)__hip_atomic_load(&flags[x0], __ATOMIC_ACQUIRE,                    \
                                    __HIP_MEMORY_SCOPE_AGENT);                       \
        } while (0)
        WAITC(0);
        float4 rb[CH];
#pragma unroll
        for (int r = 0; r < CH; ++r)
            rb[r] = *(const float4*)(outp + ((size_t)r * BB + b) * HH + 4 * lane);
#pragma unroll
        for (int r = 0; r < CH; ++r)
            *(float4*)&ring[r * HH + 4 * lane] = rb[r];
        __syncthreads();
        for (int c = 0; c < NCH; ++c) {
            if (c + 1 < NCH) {
                WAITC(c + 1);
                int t0 = (c + 1) * CH;
                int lb = ((c + 1) & 1) * (CH * HH);
                float4 sb[CH];
#pragma unroll
                for (int r = 0; r < CH; ++r)
                    sb[r] = *(const float4*)(outp + ((size_t)(t0 + r) * BB + b) * HH + 4 * lane);
#pragma unroll
                for (int r = 0; r < CH; ++r)
                    *(float4*)&ring[lb + r * HH + 4 * lane] = sb[r];
            }
            __syncthreads();
        }
        return;
    }

    // ---- consumer wave: R9 dynamics + immediate while-loop gather,
    //      packed float4 per spike (value-verified layout), same sum order ----
    int off = b * HH + lane;
    float am[4], bs[4];
#pragma unroll
    for (int j = 0; j < 4; j++) {
        am[j] = DT * clip01(tau_mem[lane + 64 * j]);
        bs[j] = DT * clip01(tau_syn[lane + 64 * j]);
    }

    float vv[4] = {0.f, 0.f, 0.f, 0.f};
    float ii[4] = {0.f, 0.f, 0.f, 0.f};
    float racc[4] = {0.f, 0.f, 0.f, 0.f};
    float zl[4] = {0.f, 0.f, 0.f, 0.f};
    float cur[4], nxt[4];
    unsigned stoff = (unsigned)off;

#define STEP()                                                                      \
    do {                                                                            \
        bool z[4];                                                                  \
        _Pragma("unroll")                                                           \
        for (int j = 0; j < 4; j++) {                                               \
            float vd = vv[j] + am[j] * (ii[j] - vv[j]);     /* v + DT*tmi*(-v+i) */ \
            float id = ii[j] - bs[j] * ii[j];               /* i - DT*tsi*i    */   \
            z[j] = (vd - 1.0f) > 0.0f;                                              \
            float zf = z[j] ? 1.0f : 0.0f;                                          \
            vv[j] = z[j] ? 0.0f : vd;                                               \
            ii[j] = (id + cur[j]) + racc[j];                /* (i_dec+xw)+rec */    \
            __builtin_nontemporal_store(zf, &outp[stoff + j * 64]);                 \
            zl[j] = zf;                                                             \
        }                                                                           \
        stoff += BH;                                                                \
        unsigned long long m0 = __ballot(z[0]);                                     \
        unsigned long long m1 = __ballot(z[1]);                                     \
        unsigned long long m2 = __ballot(z[2]);                                     \
        unsigned long long m3 = __ballot(z[3]);                                     \
        racc[0] = 0.0f; racc[1] = 0.0f; racc[2] = 0.0f; racc[3] = 0.0f;             \
        if ((m0 | m1 | m2 | m3) != 0ull) {                                          \
            unsigned long long m;                                                   \
            m = m0; while (m) { int bit = __builtin_ctzll(m); m &= m - 1;           \
                float4 e = *(const float4*)(wc + (bit << 8) + 4 * lane);            \
                racc[0] += e.x; racc[1] += e.y; racc[2] += e.z; racc[3] += e.w; }   \
            m = m1; while (m) { int bit = __builtin_ctzll(m); m &= m - 1;           \
                float4 e = *(const float4*)(wc + ((64 + bit) << 8) + 4 * lane);     \
                racc[0] += e.x; racc[1] += e.y; racc[2] += e.z; racc[3] += e.w; }   \
            m = m2; while (m) { int bit = __builtin_ctzll(m); m &= m - 1;           \
                float4 e = *(const float4*)(w_recP + ((size_t)(128 + bit) << 8) + 4 * lane); \
                racc[0] += e.x; racc[1] += e.y; racc[2] += e.z; racc[3] += e.w; }   \
            m = m3; while (m) { int bit = __builtin_ctzll(m); m &= m - 1;           \
                float4 e = *(const float4*)(w_recP + ((size_t)(192 + bit) << 8) + 4 * lane); \
                racc[0] += e.x; racc[1] += e.y; racc[2] += e.z; racc[3] += e.w; }   \
        }                                                                           \
    } while (0)

    __syncthreads();   // wcache + chunk 0 staged

    for (int c = 0; c < NCH; ++c) {
        int lb = (c & 1) * (CH * HH);
#pragma unroll
        for (int j = 0; j < 4; j++)
            cur[j] = ring[lb + lane + 64 * j];
        for (int u = 0; u < CH - 1; ++u) {
#pragma unroll
            for (int j = 0; j < 4; j++)
                nxt[j] = ring[lb + (u + 1) * HH + lane + 64 * j];
            STEP();
#pragma unroll
            for (int j = 0; j < 4; j++)
                cur[j] = nxt[j];
        }
        STEP();        // u = CH-1
        __syncthreads();
    }

    // final state: z_f, v_f, i_f (from registers)
#pragma unroll
    for (int j = 0; j < 4; j++) {
        outp[(size_t)TT * BH + b * HH + lane + 64 * j] = zl[j];
        outp[(size_t)TT * BH + BH + b * HH + lane + 64 * j] = vv[j];
        outp[(size_t)TT * BH + 2 * BH + b * HH + lane + 64 * j] = ii[j];
    }
}

extern "C" void kernel_launch(void* const* d_in, const int* in_sizes, int n_in,
                              void* d_out, int out_size, void* d_ws, size_t ws_size,
                              hipStream_t stream) {
    const float* x       = (const float*)d_in[0];
    const float* w_in    = (const float*)d_in[1];
    const float* w_rec   = (const float*)d_in[2];
    const float* tau_syn = (const float*)d_in[3];
    const float* tau_mem = (const float*)d_in[4];
    float* out = (float*)d_out;

    float* w_inT  = (float*)d_ws;              // 65536 floats
    float* w_recP = w_inT + HH * HH;           // 65536 floats
    int*   flags  = (int*)(w_recP + HH * HH);  // 1000 ints

    hipMemsetAsync(flags, 0, NXT * sizeof(int), stream);
    transpose2<<<256, 256, 0, stream>>>(w_in, w_rec, w_inT, w_recP);
    fused<<<SCANB + 2 * NXT, 256, 0, stream>>>(x, tau_syn, tau_mem, w_inT, w_recP, flags, out);
}

// Round 14
// 424.961 us; speedup vs baseline: 1.6306x; 1.1196x over previous
//
#include <hip/hip_runtime.h>

#define TT 2000
#define BB 64
#define HH 256
#define BH (BB*HH)
#define CH 8            // scan chunk = 8 time steps
#define NCH (TT/CH)     // 250 chunks
#define CROWS 128       // w_recP rows cached in LDS (s in [0,128))
#define NXT 500         // GEMM x-tiles (each covers 4 t-values x all b)
#define SCANB 64        // scan blocks (one per batch)

#define BM 256
#define BN 128
#define BK 32

__device__ __forceinline__ float clip01(float x) { return fminf(fmaxf(x, 0.0f), 1.0f); }

// ---------------- weight prep ----------------
// w_inT[k][h]     = w_in[h][k]       (GEMM)
// w_recP[s][4l+j] = w_rec[l+64j][s]  (packed gather rows; value-verified)
__global__ void transpose2(const float* __restrict__ w_in, const float* __restrict__ w_rec,
                           float* __restrict__ w_inT, float* __restrict__ w_recP) {
    int idx = blockIdx.x * 256 + threadIdx.x;   // 65536 per matrix
    int h = idx >> 8, s = idx & 255;            // coalesced read over s
    w_inT[s * HH + h] = w_in[idx];
    int l = h & 63, j = h >> 6;
    w_recP[s * HH + 4 * l + j] = w_rec[idx];
}

// ---------------- fused kernel: GEMM blocks + scan blocks, flag-synced ----------------
// blocks [0,64): scan (threads 0..127; rest exit). R13-verbatim scan.
// blocks [64,1064): GEMM 256x128 mega-tile, 512 threads (8 waves -> 2/SIMD even
//   at the LDS-forced 1 block/CU). Tile x covers n'=t*64+b in [256x,256x+256)
//   = t in {4x..4x+3}. flags[x]==2 when both h-halves stored (release).

__global__ __launch_bounds__(512) void fused(const float* __restrict__ X,
                                             const float* __restrict__ tau_syn,
                                             const float* __restrict__ tau_mem,
                                             const float* __restrict__ w_inT,
                                             const float* __restrict__ w_recP,
                                             int* flags,
                                             float* outp) {
    __shared__ __align__(16) char ldsraw[147456];   // union: scan{ring16K+wc128K} / gemm{XsT+Ws 50K}
    int gx = blockIdx.x;

    if (gx >= SCANB) {
        // ================= GEMM block (R9 math, 256x128 t-major tile) =================
        float* XsT = (float*)ldsraw;                 // [BK][BM+4]  33.3KB
        float* Ws  = XsT + BK * (BM + 4);            // [BK][BN+4]  16.9KB
        int gg = gx - SCANB;
        int xt = gg >> 1, yy = gg & 1;
        int n0 = xt * BM, h0 = yy * BN;
        int tid = threadIdx.x;
        int ty = tid >> 4, tx = tid & 15;            // ty 0..31, tx 0..15
        float acc[8][8] = {};

        for (int kc = 0; kc < HH; kc += BK) {
            {   // X tile: 256 rows x 32 k. row n' = t*64+b -> X[(b*TT + t)*HH + k]
                int r = tid & 255, kseg = (tid >> 8) * 16;
                int np = n0 + r;
                const float* src = X + ((size_t)(np & 63) * TT + (np >> 6)) * HH + kc + kseg;
#pragma unroll
                for (int q = 0; q < 4; q++) {
                    float4 xv = *(const float4*)(src + q * 4);
                    XsT[(kseg + q * 4 + 0) * (BM + 4) + r] = xv.x;
                    XsT[(kseg + q * 4 + 1) * (BM + 4) + r] = xv.y;
                    XsT[(kseg + q * 4 + 2) * (BM + 4) + r] = xv.z;
                    XsT[(kseg + q * 4 + 3) * (BM + 4) + r] = xv.w;
                }
            }
            {   // W tile: 32 k x 128 cols
                int krow = tid >> 4, cs = (tid & 15) * 8;
                const float* src = w_inT + (size_t)(kc + krow) * HH + h0 + cs;
#pragma unroll
                for (int q = 0; q < 2; q++) {
                    float4 wv = *(const float4*)(src + q * 4);
                    *(float4*)&Ws[krow * (BN + 4) + cs + q * 4] = wv;
                }
            }
            __syncthreads();
#pragma unroll 4
            for (int kk = 0; kk < BK; kk++) {
                float4 a0 = *(const float4*)&XsT[kk * (BM + 4) + ty * 8];
                float4 a1 = *(const float4*)&XsT[kk * (BM + 4) + ty * 8 + 4];
                float4 b0 = *(const float4*)&Ws[kk * (BN + 4) + tx * 8];
                float4 b1 = *(const float4*)&Ws[kk * (BN + 4) + tx * 8 + 4];
                float a[8] = {a0.x, a0.y, a0.z, a0.w, a1.x, a1.y, a1.z, a1.w};
                float bb[8] = {b0.x, b0.y, b0.z, b0.w, b1.x, b1.y, b1.z, b1.w};
#pragma unroll
                for (int r = 0; r < 8; r++)
#pragma unroll
                    for (int c = 0; c < 8; c++)
                        acc[r][c] += a[r] * bb[c];
            }
            __syncthreads();
        }
#pragma unroll
        for (int r = 0; r < 8; r++) {
            int np = n0 + ty * 8 + r;                 // n' IS the out row (t*BB+b)
            float* dst = outp + (size_t)np * HH + h0 + tx * 8;
            float4 s0 = {acc[r][0], acc[r][1], acc[r][2], acc[r][3]};
            float4 s1 = {acc[r][4], acc[r][5], acc[r][6], acc[r][7]};
            *(float4*)dst = s0;
            *(float4*)(dst + 4) = s1;
        }
        __syncthreads();   // all waves' stores drained (vmcnt(0) before barrier)
        if (tid == 0)
            __hip_atomic_fetch_add(&flags[xt], 1, __ATOMIC_RELEASE, __HIP_MEMORY_SCOPE_AGENT);
        return;
    }

    // ================= scan block (R13-verbatim) =================
    if (threadIdx.x >= 128) return;   // waves 2..7 unused (exit before any barrier)
    const float DT = 0.001f;
    float* ring = (float*)ldsraw;                  // 2*CH*HH floats = 16 KB
    float* wc   = ring + 2 * CH * HH;              // CROWS*HH floats = 128 KB
    int b = gx;
    int lane = threadIdx.x & 63;
    int wid = threadIdx.x >> 6;

    // cooperative wcache fill: w_recP rows 0..127 (128 threads, 64 iters)
    {
        const float4* src = (const float4*)w_recP;
        float4* dst = (float4*)wc;
#pragma unroll
        for (int q = 0; q < (CROWS * HH / 4) / 128; ++q)
            dst[q * 128 + threadIdx.x] = src[q * 128 + threadIdx.x];
    }

    if (wid == 1) {
        // ---- producer: flag-wait then stage xw chunks into LDS ring ----
        // chunk c needs t in [8c,8c+8) -> x-tiles 2c, 2c+1 (each ==2 when done)
#define WAITC(CC) do { int x0 = 2 * (CC);                                            \
            _Pragma("unroll")                                                        \
            for (int k = 0; k < 2; ++k)                                              \
                while (__hip_atomic_load(&flags[x0 + k], __ATOMIC_RELAXED,           \
                                         __HIP_MEMORY_SCOPE_AGENT) != 2)             \
                    __builtin_amdgcn_s_sleep(8);                                     \
            (void)__hip_atomic_load(&flags[x0], __ATOMIC_ACQUIRE,                    \
                                    __HIP_MEMORY_SCOPE_AGENT);                       \
        } while (0)
        WAITC(0);
        float4 rb[CH];
#pragma unroll
        for (int r = 0; r < CH; ++r)
            rb[r] = *(const float4*)(outp + ((size_t)r * BB + b) * HH + 4 * lane);
#pragma unroll
        for (int r = 0; r < CH; ++r)
            *(float4*)&ring[r * HH + 4 * lane] = rb[r];
        __syncthreads();
        for (int c = 0; c < NCH; ++c) {
            if (c + 1 < NCH) {
                WAITC(c + 1);
                int t0 = (c + 1) * CH;
                int lb = ((c + 1) & 1) * (CH * HH);
                float4 sb[CH];
#pragma unroll
                for (int r = 0; r < CH; ++r)
                    sb[r] = *(const float4*)(outp + ((size_t)(t0 + r) * BB + b) * HH + 4 * lane);
#pragma unroll
                for (int r = 0; r < CH; ++r)
                    *(float4*)&ring[lb + r * HH + 4 * lane] = sb[r];
            }
            __syncthreads();
        }
        return;
    }

    // ---- consumer wave: R9 dynamics + immediate while-loop gather,
    //      packed float4 per spike, ascending m0,m1,m2,m3 sum order ----
    int off = b * HH + lane;
    float am[4], bs[4];
#pragma unroll
    for (int j = 0; j < 4; j++) {
        am[j] = DT * clip01(tau_mem[lane + 64 * j]);
        bs[j] = DT * clip01(tau_syn[lane + 64 * j]);
    }

    float vv[4] = {0.f, 0.f, 0.f, 0.f};
    float ii[4] = {0.f, 0.f, 0.f, 0.f};
    float racc[4] = {0.f, 0.f, 0.f, 0.f};
    float zl[4] = {0.f, 0.f, 0.f, 0.f};
    float cur[4], nxt[4];
    unsigned stoff = (unsigned)off;

#define STEP()                                                                      \
    do {                                                                            \
        bool z[4];                                                                  \
        _Pragma("unroll")                                                           \
        for (int j = 0; j < 4; j++) {                                               \
            float vd = vv[j] + am[j] * (ii[j] - vv[j]);     /* v + DT*tmi*(-v+i) */ \
            float id = ii[j] - bs[j] * ii[j];               /* i - DT*tsi*i    */   \
            z[j] = (vd - 1.0f) > 0.0f;                                              \
            float zf = z[j] ? 1.0f : 0.0f;                                          \
            vv[j] = z[j] ? 0.0f : vd;                                               \
            ii[j] = (id + cur[j]) + racc[j];                /* (i_dec+xw)+rec */    \
            __builtin_nontemporal_store(zf, &outp[stoff + j * 64]);                 \
            zl[j] = zf;                                                             \
        }                                                                           \
        stoff += BH;                                                                \
        unsigned long long m0 = __ballot(z[0]);                                     \
        unsigned long long m1 = __ballot(z[1]);                                     \
        unsigned long long m2 = __ballot(z[2]);                                     \
        unsigned long long m3 = __ballot(z[3]);                                     \
        racc[0] = 0.0f; racc[1] = 0.0f; racc[2] = 0.0f; racc[3] = 0.0f;             \
        if ((m0 | m1 | m2 | m3) != 0ull) {                                          \
            unsigned long long m;                                                   \
            m = m0; while (m) { int bit = __builtin_ctzll(m); m &= m - 1;           \
                float4 e = *(const float4*)(wc + (bit << 8) + 4 * lane);            \
                racc[0] += e.x; racc[1] += e.y; racc[2] += e.z; racc[3] += e.w; }   \
            m = m1; while (m) { int bit = __builtin_ctzll(m); m &= m - 1;           \
                float4 e = *(const float4*)(wc + ((64 + bit) << 8) + 4 * lane);     \
                racc[0] += e.x; racc[1] += e.y; racc[2] += e.z; racc[3] += e.w; }   \
            m = m2; while (m) { int bit = __builtin_ctzll(m); m &= m - 1;           \
                float4 e = *(const float4*)(w_recP + ((size_t)(128 + bit) << 8) + 4 * lane); \
                racc[0] += e.x; racc[1] += e.y; racc[2] += e.z; racc[3] += e.w; }   \
            m = m3; while (m) { int bit = __builtin_ctzll(m); m &= m - 1;           \
                float4 e = *(const float4*)(w_recP + ((size_t)(192 + bit) << 8) + 4 * lane); \
                racc[0] += e.x; racc[1] += e.y; racc[2] += e.z; racc[3] += e.w; }   \
        }                                                                           \
    } while (0)

    __syncthreads();   // wcache + chunk 0 staged

    for (int c = 0; c < NCH; ++c) {
        int lb = (c & 1) * (CH * HH);
#pragma unroll
        for (int j = 0; j < 4; j++)
            cur[j] = ring[lb + lane + 64 * j];
        for (int u = 0; u < CH - 1; ++u) {
#pragma unroll
            for (int j = 0; j < 4; j++)
                nxt[j] = ring[lb + (u + 1) * HH + lane + 64 * j];
            STEP();
#pragma unroll
            for (int j = 0; j < 4; j++)
                cur[j] = nxt[j];
        }
        STEP();        // u = CH-1
        __syncthreads();
    }

    // final state: z_f, v_f, i_f (from registers)
#pragma unroll
    for (int j = 0; j < 4; j++) {
        outp[(size_t)TT * BH + b * HH + lane + 64 * j] = zl[j];
        outp[(size_t)TT * BH + BH + b * HH + lane + 64 * j] = vv[j];
        outp[(size_t)TT * BH + 2 * BH + b * HH + lane + 64 * j] = ii[j];
    }
}

extern "C" void kernel_launch(void* const* d_in, const int* in_sizes, int n_in,
                              void* d_out, int out_size, void* d_ws, size_t ws_size,
                              hipStream_t stream) {
    const float* x       = (const float*)d_in[0];
    const float* w_in    = (const float*)d_in[1];
    const float* w_rec   = (const float*)d_in[2];
    const float* tau_syn = (const float*)d_in[3];
    const float* tau_mem = (const float*)d_in[4];
    float* out = (float*)d_out;

    float* w_inT  = (float*)d_ws;              // 65536 floats
    float* w_recP = w_inT + HH * HH;           // 65536 floats
    int*   flags  = (int*)(w_recP + HH * HH);  // 500 ints

    hipMemsetAsync(flags, 0, NXT * sizeof(int), stream);
    transpose2<<<256, 256, 0, stream>>>(w_in, w_rec, w_inT, w_recP);
    fused<<<SCANB + 2 * NXT, 512, 0, stream>>>(x, tau_syn, tau_mem, w_inT, w_recP, flags, out);
}

// Round 15
// 401.411 us; speedup vs baseline: 1.7263x; 1.0587x over previous
//
#include <hip/hip_runtime.h>

#define TT 2000
#define BB 64
#define HH 256
#define BH (BB*HH)
#define CH 8            // scan chunk = 8 time steps
#define NCH (TT/CH)     // 250 chunks
#define CROWS 128       // w_recP rows cached in LDS (s in [0,128))
#define NXT 500         // GEMM x-tiles (each covers 4 t-values x all b)
#define SCANB 64        // scan blocks (one per batch)

#define BM 256
#define BN 128
#define BK 32
#define NKS (HH/BK)     // 8 K-steps

__device__ __forceinline__ float clip01(float x) { return fminf(fmaxf(x, 0.0f), 1.0f); }

// ---------------- weight prep ----------------
// w_inT[k][h]     = w_in[h][k]       (GEMM)
// w_recP[s][4l+j] = w_rec[l+64j][s]  (packed gather rows; value-verified)
__global__ void transpose2(const float* __restrict__ w_in, const float* __restrict__ w_rec,
                           float* __restrict__ w_inT, float* __restrict__ w_recP) {
    int idx = blockIdx.x * 256 + threadIdx.x;   // 65536 per matrix
    int h = idx >> 8, s = idx & 255;            // coalesced read over s
    w_inT[s * HH + h] = w_in[idx];
    int l = h & 63, j = h >> 6;
    w_recP[s * HH + 4 * l + j] = w_rec[idx];
}

// ---------------- fused kernel: GEMM blocks + scan blocks, flag-synced ----------------
// blocks [0,64): scan (threads 0..127; rest exit). R13-verbatim scan.
// blocks [64,1064): GEMM 256x128 tile, 512 threads, SOFTWARE-PIPELINED staging:
//   global loads for K-step s+1 issued before computing step s (reg-staged),
//   hiding the lane-per-row X load latency under the FMA phase.
//   Tile x covers n'=t*64+b in [256x,256x+256) = t in {4x..4x+3}.
//   flags[x]==2 when both h-halves stored (release).

__global__ __launch_bounds__(512) void fused(const float* __restrict__ X,
                                             const float* __restrict__ tau_syn,
                                             const float* __restrict__ tau_mem,
                                             const float* __restrict__ w_inT,
                                             const float* __restrict__ w_recP,
                                             int* flags,
                                             float* outp) {
    __shared__ __align__(16) char ldsraw[147456];   // union: scan{ring16K+wc128K} / gemm{XsT+Ws 50K}
    int gx = blockIdx.x;

    if (gx >= SCANB) {
        // ================= GEMM block (R9 math, pipelined staging) =================
        float* XsT = (float*)ldsraw;                 // [BK][BM+4]  33.3KB
        float* Ws  = XsT + BK * (BM + 4);            // [BK][BN+4]  16.9KB
        int gg = gx - SCANB;
        int xt = gg >> 1, yy = gg & 1;
        int n0 = xt * BM, h0 = yy * BN;
        int tid = threadIdx.x;
        int ty = tid >> 4, tx = tid & 15;            // ty 0..31, tx 0..15
        float acc[8][8] = {};

        // staging geometry
        int r = tid & 255, kseg = (tid >> 8) * 16;   // X: row n0+r, 16 k's
        int np = n0 + r;
        const float* xsrc = X + ((size_t)(np & 63) * TT + (np >> 6)) * HH + kseg;
        int krow = tid >> 4, cs = (tid & 15) * 8;    // W: row kc+krow, 8 cols
        const float* wsrc = w_inT + (size_t)krow * HH + h0 + cs;

        float4 xr0, xr1, xr2, xr3, wr0, wr1;
        // prologue: issue K-step 0 loads
        xr0 = *(const float4*)(xsrc + 0);
        xr1 = *(const float4*)(xsrc + 4);
        xr2 = *(const float4*)(xsrc + 8);
        xr3 = *(const float4*)(xsrc + 12);
        wr0 = *(const float4*)(wsrc + 0);
        wr1 = *(const float4*)(wsrc + 4);

        for (int step = 0; step < NKS; ++step) {
            // write staged regs -> LDS (vmcnt wait inserted here by compiler)
            XsT[(kseg + 0) * (BM + 4) + r]  = xr0.x;
            XsT[(kseg + 1) * (BM + 4) + r]  = xr0.y;
            XsT[(kseg + 2) * (BM + 4) + r]  = xr0.z;
            XsT[(kseg + 3) * (BM + 4) + r]  = xr0.w;
            XsT[(kseg + 4) * (BM + 4) + r]  = xr1.x;
            XsT[(kseg + 5) * (BM + 4) + r]  = xr1.y;
            XsT[(kseg + 6) * (BM + 4) + r]  = xr1.z;
            XsT[(kseg + 7) * (BM + 4) + r]  = xr1.w;
            XsT[(kseg + 8) * (BM + 4) + r]  = xr2.x;
            XsT[(kseg + 9) * (BM + 4) + r]  = xr2.y;
            XsT[(kseg + 10) * (BM + 4) + r] = xr2.z;
            XsT[(kseg + 11) * (BM + 4) + r] = xr2.w;
            XsT[(kseg + 12) * (BM + 4) + r] = xr3.x;
            XsT[(kseg + 13) * (BM + 4) + r] = xr3.y;
            XsT[(kseg + 14) * (BM + 4) + r] = xr3.z;
            XsT[(kseg + 15) * (BM + 4) + r] = xr3.w;
            *(float4*)&Ws[krow * (BN + 4) + cs]     = wr0;
            *(float4*)&Ws[krow * (BN + 4) + cs + 4] = wr1;
            __syncthreads();
            // issue NEXT K-step loads (in flight during compute below)
            if (step + 1 < NKS) {
                const float* xs = xsrc + (step + 1) * BK;
                const float* ws = wsrc + (size_t)(step + 1) * BK * HH;
                xr0 = *(const float4*)(xs + 0);
                xr1 = *(const float4*)(xs + 4);
                xr2 = *(const float4*)(xs + 8);
                xr3 = *(const float4*)(xs + 12);
                wr0 = *(const float4*)(ws + 0);
                wr1 = *(const float4*)(ws + 4);
            }
            // compute this K-step (kk ascending; same FMA order as R9)
#pragma unroll 4
            for (int kk = 0; kk < BK; kk++) {
                float4 a0 = *(const float4*)&XsT[kk * (BM + 4) + ty * 8];
                float4 a1 = *(const float4*)&XsT[kk * (BM + 4) + ty * 8 + 4];
                float4 b0 = *(const float4*)&Ws[kk * (BN + 4) + tx * 8];
                float4 b1 = *(const float4*)&Ws[kk * (BN + 4) + tx * 8 + 4];
                float a[8] = {a0.x, a0.y, a0.z, a0.w, a1.x, a1.y, a1.z, a1.w};
                float bb[8] = {b0.x, b0.y, b0.z, b0.w, b1.x, b1.y, b1.z, b1.w};
#pragma unroll
                for (int rr = 0; rr < 8; rr++)
#pragma unroll
                    for (int cc = 0; cc < 8; cc++)
                        acc[rr][cc] += a[rr] * bb[cc];
            }
            __syncthreads();
        }
#pragma unroll
        for (int rr = 0; rr < 8; rr++) {
            int npo = n0 + ty * 8 + rr;               // n' IS the out row (t*BB+b)
            float* dst = outp + (size_t)npo * HH + h0 + tx * 8;
            float4 s0 = {acc[rr][0], acc[rr][1], acc[rr][2], acc[rr][3]};
            float4 s1 = {acc[rr][4], acc[rr][5], acc[rr][6], acc[rr][7]};
            *(float4*)dst = s0;
            *(float4*)(dst + 4) = s1;
        }
        __syncthreads();   // all waves' stores drained (vmcnt(0) before barrier)
        if (tid == 0)
            __hip_atomic_fetch_add(&flags[xt], 1, __ATOMIC_RELEASE, __HIP_MEMORY_SCOPE_AGENT);
        return;
    }

    // ================= scan block (R13-verbatim) =================
    if (threadIdx.x >= 128) return;   // waves 2..7 unused (exit before any barrier)
    const float DT = 0.001f;
    float* ring = (float*)ldsraw;                  // 2*CH*HH floats = 16 KB
    float* wc   = ring + 2 * CH * HH;              // CROWS*HH floats = 128 KB
    int b = gx;
    int lane = threadIdx.x & 63;
    int wid = threadIdx.x >> 6;

    // cooperative wcache fill: w_recP rows 0..127 (128 threads, 64 iters)
    {
        const float4* src = (const float4*)w_recP;
        float4* dst = (float4*)wc;
#pragma unroll
        for (int q = 0; q < (CROWS * HH / 4) / 128; ++q)
            dst[q * 128 + threadIdx.x] = src[q * 128 + threadIdx.x];
    }

    if (wid == 1) {
        // ---- producer: flag-wait then stage xw chunks into LDS ring ----
        // chunk c needs t in [8c,8c+8) -> x-tiles 2c, 2c+1 (each ==2 when done)
#define WAITC(CC) do { int x0 = 2 * (CC);                                            \
            _Pragma("unroll")                                                        \
            for (int k = 0; k < 2; ++k)                                              \
                while (__hip_atomic_load(&flags[x0 + k], __ATOMIC_RELAXED,           \
                                         __HIP_MEMORY_SCOPE_AGENT) != 2)             \
                    __builtin_amdgcn_s_sleep(8);                                     \
            (void)__hip_atomic_load(&flags[x0], __ATOMIC_ACQUIRE,                    \
                                    __HIP_MEMORY_SCOPE_AGENT);                       \
        } while (0)
        WAITC(0);
        float4 rb[CH];
#pragma unroll
        for (int r2 = 0; r2 < CH; ++r2)
            rb[r2] = *(const float4*)(outp + ((size_t)r2 * BB + b) * HH + 4 * lane);
#pragma unroll
        for (int r2 = 0; r2 < CH; ++r2)
            *(float4*)&ring[r2 * HH + 4 * lane] = rb[r2];
        __syncthreads();
        for (int c = 0; c < NCH; ++c) {
            if (c + 1 < NCH) {
                WAITC(c + 1);
                int t0 = (c + 1) * CH;
                int lb = ((c + 1) & 1) * (CH * HH);
                float4 sb[CH];
#pragma unroll
                for (int r2 = 0; r2 < CH; ++r2)
                    sb[r2] = *(const float4*)(outp + ((size_t)(t0 + r2) * BB + b) * HH + 4 * lane);
#pragma unroll
                for (int r2 = 0; r2 < CH; ++r2)
                    *(float4*)&ring[lb + r2 * HH + 4 * lane] = sb[r2];
            }
            __syncthreads();
        }
        return;
    }

    // ---- consumer wave: R9 dynamics + immediate while-loop gather,
    //      packed float4 per spike, ascending m0,m1,m2,m3 sum order ----
    int off = b * HH + lane;
    float am[4], bs[4];
#pragma unroll
    for (int j = 0; j < 4; j++) {
        am[j] = DT * clip01(tau_mem[lane + 64 * j]);
        bs[j] = DT * clip01(tau_syn[lane + 64 * j]);
    }

    float vv[4] = {0.f, 0.f, 0.f, 0.f};
    float ii[4] = {0.f, 0.f, 0.f, 0.f};
    float racc[4] = {0.f, 0.f, 0.f, 0.f};
    float zl[4] = {0.f, 0.f, 0.f, 0.f};
    float cur[4], nxt[4];
    unsigned stoff = (unsigned)off;

#define STEP()                                                                      \
    do {                                                                            \
        bool z[4];                                                                  \
        _Pragma("unroll")                                                           \
        for (int j = 0; j < 4; j++) {                                               \
            float vd = vv[j] + am[j] * (ii[j] - vv[j]);     /* v + DT*tmi*(-v+i) */ \
            float id = ii[j] - bs[j] * ii[j];               /* i - DT*tsi*i    */   \
            z[j] = (vd - 1.0f) > 0.0f;                                              \
            float zf = z[j] ? 1.0f : 0.0f;                                          \
            vv[j] = z[j] ? 0.0f : vd;                                               \
            ii[j] = (id + cur[j]) + racc[j];                /* (i_dec+xw)+rec */    \
            __builtin_nontemporal_store(zf, &outp[stoff + j * 64]);                 \
            zl[j] = zf;                                                             \
        }                                                                           \
        stoff += BH;                                                                \
        unsigned long long m0 = __ballot(z[0]);                                     \
        unsigned long long m1 = __ballot(z[1]);                                     \
        unsigned long long m2 = __ballot(z[2]);                                     \
        unsigned long long m3 = __ballot(z[3]);                                     \
        racc[0] = 0.0f; racc[1] = 0.0f; racc[2] = 0.0f; racc[3] = 0.0f;             \
        if ((m0 | m1 | m2 | m3) != 0ull) {                                          \
            unsigned long long m;                                                   \
            m = m0; while (m) { int bit = __builtin_ctzll(m); m &= m - 1;           \
                float4 e = *(const float4*)(wc + (bit << 8) + 4 * lane);            \
                racc[0] += e.x; racc[1] += e.y; racc[2] += e.z; racc[3] += e.w; }   \
            m = m1; while (m) { int bit = __builtin_ctzll(m); m &= m - 1;           \
                float4 e = *(const float4*)(wc + ((64 + bit) << 8) + 4 * lane);     \
                racc[0] += e.x; racc[1] += e.y; racc[2] += e.z; racc[3] += e.w; }   \
            m = m2; while (m) { int bit = __builtin_ctzll(m); m &= m - 1;           \
                float4 e = *(const float4*)(w_recP + ((size_t)(128 + bit) << 8) + 4 * lane); \
                racc[0] += e.x; racc[1] += e.y; racc[2] += e.z; racc[3] += e.w; }   \
            m = m3; while (m) { int bit = __builtin_ctzll(m); m &= m - 1;           \
                float4 e = *(const float4*)(w_recP + ((size_t)(192 + bit) << 8) + 4 * lane); \
                racc[0] += e.x; racc[1] += e.y; racc[2] += e.z; racc[3] += e.w; }   \
        }                                                                           \
    } while (0)

    __syncthreads();   // wcache + chunk 0 staged

    for (int c = 0; c < NCH; ++c) {
        int lb = (c & 1) * (CH * HH);
#pragma unroll
        for (int j = 0; j < 4; j++)
            cur[j] = ring[lb + lane + 64 * j];
        for (int u = 0; u < CH - 1; ++u) {
#pragma unroll
            for (int j = 0; j < 4; j++)
                nxt[j] = ring[lb + (u + 1) * HH + lane + 64 * j];
            STEP();
#pragma unroll
            for (int j = 0; j < 4; j++)
                cur[j] = nxt[j];
        }
        STEP();        // u = CH-1
        __syncthreads();
    }

    // final state: z_f, v_f, i_f (from registers)
#pragma unroll
    for (int j = 0; j < 4; j++) {
        outp[(size_t)TT * BH + b * HH + lane + 64 * j] = zl[j];
        outp[(size_t)TT * BH + BH + b * HH + lane + 64 * j] = vv[j];
        outp[(size_t)TT * BH + 2 * BH + b * HH + lane + 64 * j] = ii[j];
    }
}

extern "C" void kernel_launch(void* const* d_in, const int* in_sizes, int n_in,
                              void* d_out, int out_size, void* d_ws, size_t ws_size,
                              hipStream_t stream) {
    const float* x       = (const float*)d_in[0];
    const float* w_in    = (const float*)d_in[1];
    const float* w_rec   = (const float*)d_in[2];
    const float* tau_syn = (const float*)d_in[3];
    const float* tau_mem = (const float*)d_in[4];
    float* out = (float*)d_out;

    float* w_inT  = (float*)d_ws;              // 65536 floats
    float* w_recP = w_inT + HH * HH;           // 65536 floats
    int*   flags  = (int*)(w_recP + HH * HH);  // 500 ints

    hipMemsetAsync(flags, 0, NXT * sizeof(int), stream);
    transpose2<<<256, 256, 0, stream>>>(w_in, w_rec, w_inT, w_recP);
    fused<<<SCANB + 2 * NXT, 512, 0, stream>>>(x, tau_syn, tau_mem, w_inT, w_recP, flags, out);
}